// Round 2
// baseline (513.296 us; speedup 1.0000x reference)
//
#include <hip/hip_runtime.h>
#include <hip/hip_bf16.h>
#include <math.h>

namespace {
constexpr int Ln   = 2048;
constexpr int Kn   = 32;
constexpr int EFn  = 128;
constexpr int ROWS = 4 * Ln;                               // 8192
constexpr size_t V_ELEMS = (size_t)ROWS * EFn;             // 1048576
constexpr size_t E_ELEMS = (size_t)ROWS * Kn * EFn;        // 33554432
constexpr size_t IDX_OFF = V_ELEMS + E_ELEMS;              // 34603008

__device__ __forceinline__ unsigned int orderKey(float f) {
  unsigned int u = __float_as_uint(f);
  return (u & 0x80000000u) ? ~u : (u | 0x80000000u);
}
__device__ __forceinline__ float keyToFloat(unsigned int k) {
  unsigned int u = (k & 0x80000000u) ? (k & 0x7fffffffu) : ~k;
  return __uint_as_float(u);
}
__device__ __forceinline__ unsigned long long u64min(unsigned long long a, unsigned long long b) {
  return a < b ? a : b;
}
} // namespace

// T[n][d][c] = sum_m (pos_W[d,m] + pos_b[m]) * edge_W[n*16+m, c]   (7*66*128 f32 = 236,544 B)
__global__ void pf_tab(const float* __restrict__ pos_W, const float* __restrict__ pos_b,
                       const float* __restrict__ edge_W, float* __restrict__ T) {
  int n = blockIdx.x / 66, dd = blockIdx.x % 66, c = threadIdx.x;
  float acc = 0.f;
#pragma unroll
  for (int m = 0; m < 16; m++)
    acc += (pos_W[dd * 16 + m] + pos_b[m]) * edge_W[(n * 16 + m) * EFn + c];
  T[(size_t)(n * 66 + dd) * EFn + c] = acc;
}

__global__ __launch_bounds__(256) void pf_main(
    const float* __restrict__ dist_ca, const float* __restrict__ omega,
    const float* __restrict__ theta, const float* __restrict__ phi,
    const float* __restrict__ dihedral, const float* __restrict__ mask_angle,
    const int* __restrict__ Sarr, const int* __restrict__ ridx,
    const int* __restrict__ chain, const float* __restrict__ T,
    const float* __restrict__ edge_W, const float* __restrict__ ln_e_g,
    const float* __restrict__ ln_e_b, const float* __restrict__ embed_tab,
    const float* __restrict__ node_W, const float* __restrict__ node_b,
    const float* __restrict__ ln_n_g, const float* __restrict__ ln_n_b,
    float* __restrict__ out) {
  __shared__ unsigned int s_keys[Ln];          // 8 KB, for exact fallback
  __shared__ unsigned int s_hist[256];
  __shared__ unsigned long long s_cand[64];
  __shared__ unsigned long long s_w64[4];
  __shared__ float s_mx[4], s_mn2[4], s_mx2[4];
  __shared__ float s_v4[4];
  __shared__ int s_nidx[Kn];
  __shared__ float s_nval[Kn];
  __shared__ int s_d7[Kn * 8];
  __shared__ int s_bsel, s_tot, s_cnt;

  const int tid = threadIdx.x;
  const int lane = tid & 63, wid = tid >> 6;
  const int r = blockIdx.x;                    // row = b*L + i
  const int b = r >> 11;
  const size_t rowoff = (size_t)r * Ln;

  // ---------- Phase 1: load row, D = mask*dist, row max ----------
  float Dv[8], Mv[8];
  float lmax = -3.4e38f;
#pragma unroll
  for (int m = 0; m < 8; m++) {
    int j = tid + (m << 8);
    float mk = mask_angle[rowoff + j];
    float dd = mk * dist_ca[rowoff + j];
    Dv[m] = dd; Mv[m] = mk;
    lmax = fmaxf(lmax, dd);
  }
#pragma unroll
  for (int o = 32; o; o >>= 1) lmax = fmaxf(lmax, __shfl_xor(lmax, o));
  if (!lane) s_mx[wid] = lmax;
  __syncthreads();
  const float Dmax = fmaxf(fmaxf(s_mx[0], s_mx[1]), fmaxf(s_mx[2], s_mx[3]));

  // ---------- Phase 2: adjust, keys, min/max for bucketing ----------
  float lmin = 3.4e38f; lmax = -3.4e38f;
#pragma unroll
  for (int m = 0; m < 8; m++) {
    float adj = Dv[m] + (1.0f - Mv[m]) * Dmax;
    Dv[m] = adj;
    s_keys[tid + (m << 8)] = orderKey(adj);
    lmin = fminf(lmin, adj); lmax = fmaxf(lmax, adj);
  }
#pragma unroll
  for (int o = 32; o; o >>= 1) {
    lmin = fminf(lmin, __shfl_xor(lmin, o));
    lmax = fmaxf(lmax, __shfl_xor(lmax, o));
  }
  if (!lane) { s_mn2[wid] = lmin; s_mx2[wid] = lmax; }
  s_hist[tid] = 0u;
  __syncthreads();
  const float m0 = fminf(fminf(s_mn2[0], s_mn2[1]), fminf(s_mn2[2], s_mn2[3]));
  const float M0 = fmaxf(fmaxf(s_mx2[0], s_mx2[1]), fmaxf(s_mx2[2], s_mx2[3]));
  const float rng = M0 - m0;
  const float scale = (rng > 0.f) ? 255.0f / rng : 0.f;

  // ---------- Phase 3: bucket histogram ----------
  int binv[8];
#pragma unroll
  for (int m = 0; m < 8; m++) {
    int bin = (int)((Dv[m] - m0) * scale);
    bin = bin < 0 ? 0 : (bin > 255 ? 255 : bin);
    binv[m] = bin;
    atomicAdd(&s_hist[bin], 1u);
  }
  __syncthreads();
  // inclusive scan of 256 bins
  for (int off = 1; off < 256; off <<= 1) {
    unsigned int u = 0;
    if (tid >= off) u = s_hist[tid - off];
    __syncthreads();
    if (tid >= off) s_hist[tid] += u;
    __syncthreads();
  }
  {
    unsigned int cum = s_hist[tid];
    unsigned int cump = tid ? s_hist[tid - 1] : 0u;
    if (cum >= (unsigned)Kn && cump < (unsigned)Kn) { s_bsel = tid; s_tot = (int)cum; }
    if (!tid) s_cnt = 0;
  }
  __syncthreads();
  const int bsel = s_bsel;
  const int tot = s_tot;

  // ---------- Phase 4: collect candidates (fast path) ----------
  if (tot <= 64) {
#pragma unroll
    for (int m = 0; m < 8; m++) {
      if (binv[m] <= bsel) {
        int p = atomicAdd(&s_cnt, 1);
        s_cand[p] = ((unsigned long long)orderKey(Dv[m]) << 16) | (unsigned)(tid + (m << 8));
      }
    }
  }
  __syncthreads();

  if (tot <= 64) {
    // 64-lane bitonic sort ascending on (key,idx) — matches jax top_k tie-break
    if (tid < 64) {
      unsigned long long v = (tid < tot) ? s_cand[tid] : ~0ull;
#pragma unroll
      for (int size = 2; size <= 64; size <<= 1) {
        for (int stride = size >> 1; stride > 0; stride >>= 1) {
          unsigned long long p = __shfl_xor(v, stride);
          bool keepMin = (((tid & stride) == 0) == ((tid & size) == 0));
          v = ((v < p) != keepMin) ? p : v;
        }
      }
      if (tid < Kn) {
        s_nidx[tid] = (int)(v & 0xffffull);
        s_nval[tid] = keyToFloat((unsigned int)(v >> 16));
      }
    }
  } else {
    // exact fallback: 32x block-wide argmin extraction (rare: degenerate rows)
    for (int t = 0; t < Kn; t++) {
      unsigned long long lm = ~0ull;
#pragma unroll
      for (int m = 0; m < 8; m++) {
        int j = tid + (m << 8);
        unsigned long long kk = ((unsigned long long)s_keys[j] << 16) | (unsigned)j;
        lm = u64min(lm, kk);
      }
#pragma unroll
      for (int o = 32; o; o >>= 1) lm = u64min(lm, __shfl_xor(lm, o));
      if (!lane) s_w64[wid] = lm;
      __syncthreads();
      unsigned long long g = u64min(u64min(s_w64[0], s_w64[1]), u64min(s_w64[2], s_w64[3]));
      int j = (int)(g & 0xffffull);
      if (tid == (j & 255)) s_keys[j] = 0xffffffffu;  // invalidate
      if (!tid) { s_nidx[t] = j; s_nval[t] = keyToFloat((unsigned int)(g >> 16)); }
      __syncthreads();
    }
  }
  __syncthreads();

  // ---------- E_idx output (f32 values) ----------
  if (tid < Kn)
    out[IDX_OFF + (size_t)r * Kn + tid] = (float)s_nidx[tid];

  // ---------- Phase 5: per-edge table indices d[0..6] ----------
  const int ri_i = ridx[r];
  const int ch_i = chain[r];
  if (tid < Kn) {
    int j = s_nidx[tid];
    int rj = ridx[(size_t)b * Ln + j];
    int sc = (ch_i == chain[(size_t)b * Ln + j]) ? 1 : 0;
    int e0 = (int)((float)(ri_i - rj));       // trunc toward zero like .astype(int32)
    int d0 = e0 + 32; d0 = d0 < 0 ? 0 : (d0 > 64 ? 64 : d0);
    s_d7[tid * 8 + 0] = sc ? d0 : 65;
    size_t pij = rowoff + j;
    float om = omega[pij], th = theta[pij], ph = phi[pij];
    float vals[6] = { cosf(om), sinf(om), cosf(th), sinf(th), cosf(ph), sinf(ph) };
#pragma unroll
    for (int n = 0; n < 6; n++) {
      int e = (int)vals[n];                    // trunc toward zero
      int d = e + 32; d = d < 0 ? 0 : (d > 64 ? 64 : d);
      s_d7[tid * 8 + 1 + n] = sc ? d : 65;
    }
  }
  __syncthreads();

  // ---------- Phase 6: edge features: 32 edges x 8 threads x 16 channels ----------
  {
    const int k = tid >> 3, sub = tid & 7, c0 = sub << 4;
    float acc[16];
    {
      const float* Tp = T + (size_t)s_d7[k * 8 + 0] * EFn + c0;
#pragma unroll
      for (int m = 0; m < 16; m++) acc[m] = Tp[m];
    }
#pragma unroll
    for (int n = 1; n < 7; n++) {
      const float* Tp = T + (size_t)(n * 66 + s_d7[k * 8 + n]) * EFn + c0;
#pragma unroll
      for (int m = 0; m < 16; m++) acc[m] += Tp[m];
    }
    const float dv = s_nval[k];
#pragma unroll
    for (int rr = 0; rr < 16; rr++) {
      float mu = 2.0f + (20.0f / 15.0f) * (float)rr;
      float t = (dv - mu) * 0.8f;             // 1/1.25
      float rb = expf(-t * t);
      const float* W2 = edge_W + (size_t)(112 + rr) * EFn + c0;
#pragma unroll
      for (int m = 0; m < 16; m++) acc[m] = fmaf(rb, W2[m], acc[m]);
    }
    // LayerNorm over 128 channels = 8 consecutive lanes
    float s1 = 0.f, s2 = 0.f;
#pragma unroll
    for (int m = 0; m < 16; m++) { s1 += acc[m]; s2 += acc[m] * acc[m]; }
#pragma unroll
    for (int o = 1; o < 8; o <<= 1) { s1 += __shfl_xor(s1, o); s2 += __shfl_xor(s2, o); }
    const float mean = s1 * (1.0f / 128.0f);
    float var = s2 * (1.0f / 128.0f) - mean * mean;
    var = fmaxf(var, 0.f);
    const float inv = rsqrtf(var + 1e-5f);
    float y[16];
#pragma unroll
    for (int m = 0; m < 16; m++)
      y[m] = (acc[m] - mean) * inv * ln_e_g[c0 + m] + ln_e_b[c0 + m];
    float4* dst = (float4*)(out + V_ELEMS + ((size_t)(r * Kn + k) * EFn + c0));
    dst[0] = make_float4(y[0],  y[1],  y[2],  y[3]);
    dst[1] = make_float4(y[4],  y[5],  y[6],  y[7]);
    dst[2] = make_float4(y[8],  y[9],  y[10], y[11]);
    dst[3] = make_float4(y[12], y[13], y[14], y[15]);
  }

  // ---------- Phase 7: node features V ----------
  float a = 0.f;
  if (tid < EFn) {
    const int c = tid;
    const int sv = Sarr[r];
    a = node_b[c];
#pragma unroll
    for (int m = 0; m < 6; m++) a = fmaf(embed_tab[sv * 6 + m], node_W[m * EFn + c], a);
#pragma unroll
    for (int m = 0; m < 6; m++) a = fmaf(dihedral[(size_t)r * 6 + m], node_W[(6 + m) * EFn + c], a);
    float s1 = a, s2 = a * a;
#pragma unroll
    for (int o = 32; o; o >>= 1) { s1 += __shfl_xor(s1, o); s2 += __shfl_xor(s2, o); }
    if (!lane) { s_v4[wid * 2] = s1; s_v4[wid * 2 + 1] = s2; }
  }
  __syncthreads();
  if (tid < EFn) {
    const float S1 = s_v4[0] + s_v4[2], S2 = s_v4[1] + s_v4[3];
    const float mean = S1 * (1.0f / 128.0f);
    float var = S2 * (1.0f / 128.0f) - mean * mean;
    var = fmaxf(var, 0.f);
    const float inv = rsqrtf(var + 1e-5f);
    const float yv = (a - mean) * inv * ln_n_g[tid] + ln_n_b[tid];
    out[(size_t)r * EFn + tid] = yv;
  }
}

extern "C" void kernel_launch(void* const* d_in, const int* in_sizes, int n_in,
                              void* d_out, int out_size, void* d_ws, size_t ws_size,
                              hipStream_t stream) {
  (void)in_sizes; (void)n_in; (void)out_size; (void)ws_size;
  const float* dist_ca    = (const float*)d_in[0];
  const float* omega      = (const float*)d_in[1];
  const float* theta      = (const float*)d_in[2];
  const float* phi        = (const float*)d_in[3];
  const float* dihedral   = (const float*)d_in[4];
  const float* mask_angle = (const float*)d_in[5];
  // d_in[6] = mask (unused by reference)
  const int*   S          = (const int*)d_in[7];
  const int*   ridx       = (const int*)d_in[8];
  const int*   chain      = (const int*)d_in[9];
  const float* pos_W      = (const float*)d_in[10];
  const float* pos_b      = (const float*)d_in[11];
  const float* edge_W     = (const float*)d_in[12];
  const float* ln_e_g     = (const float*)d_in[13];
  const float* ln_e_b     = (const float*)d_in[14];
  const float* embed_tab  = (const float*)d_in[15];
  const float* node_W     = (const float*)d_in[16];
  const float* node_b     = (const float*)d_in[17];
  const float* ln_n_g     = (const float*)d_in[18];
  const float* ln_n_b     = (const float*)d_in[19];

  float* T = (float*)d_ws;   // 7*66*128*4 = 236,544 bytes

  pf_tab<<<7 * 66, 128, 0, stream>>>(pos_W, pos_b, edge_W, T);
  pf_main<<<ROWS, 256, 0, stream>>>(dist_ca, omega, theta, phi, dihedral, mask_angle,
                                    S, ridx, chain, T, edge_W, ln_e_g, ln_e_b,
                                    embed_tab, node_W, node_b, ln_n_g, ln_n_b,
                                    (float*)d_out);
}